// Round 1
// baseline (477.653 us; speedup 1.0000x reference)
//
#include <hip/hip_runtime.h>

// ---------- helpers ----------
typedef __bf16 bf16x8 __attribute__((ext_vector_type(8)));
typedef float f32x4 __attribute__((ext_vector_type(4)));

__device__ __forceinline__ unsigned short f2bf(float f) {
  unsigned u = __float_as_uint(f);
  u += 0x7FFFu + ((u >> 16) & 1u);   // RNE
  return (unsigned short)(u >> 16);
}
__device__ __forceinline__ float bf2f(unsigned short h) {
  return __uint_as_float(((unsigned)h) << 16);
}

__device__ __forceinline__ void gload_lds16(const void* g, void* l) {
  __builtin_amdgcn_global_load_lds((const __attribute__((address_space(1))) void*)g,
                                   (__attribute__((address_space(3))) void*)l,
                                   16, 0, 0);
}

#define NPTS 4096
#define LDX 544   // padded K for stage GEMM1 (524->544, 513->544)

// ---------- weight transpose + bf16 convert: src fp32 [Ksrc][512] -> dst u16 [512][Kpad]
__global__ __launch_bounds__(256) void convw_kernel(const float* __restrict__ src,
                                                    unsigned short* __restrict__ dst,
                                                    int Ksrc, int Kpad) {
  __shared__ float tile[32][33];
  int k0 = blockIdx.x * 32, n0 = blockIdx.y * 32;
  int tx = threadIdx.x & 31, ty = threadIdx.x >> 5;  // 32 x 8
#pragma unroll
  for (int r = 0; r < 32; r += 8) {
    int k = k0 + ty + r, n = n0 + tx;
    tile[ty + r][tx] = (k < Ksrc) ? src[(size_t)k * 512 + n] : 0.f;
  }
  __syncthreads();
#pragma unroll
  for (int r = 0; r < 32; r += 8) {
    int n = n0 + ty + r, k = k0 + tx;
    dst[(size_t)n * Kpad + k] = f2bf(tile[tx][ty + r]);
  }
}

// ---------- latent fp32 [M][512] -> X bf16 cols 0..511 (row stride LDX)
__global__ __launch_bounds__(256) void conv_latent_kernel(const float* __restrict__ latent,
                                                          unsigned short* __restrict__ X) {
  size_t idx = (size_t)blockIdx.x * 256 + threadIdx.x;  // over M*128 float4 groups
  size_t m = idx >> 7;
  int c4 = (int)(idx & 127) * 4;
  float4 v = *(const float4*)(latent + m * 512 + c4);
  ushort4 o;
  o.x = f2bf(v.x); o.y = f2bf(v.y); o.z = f2bf(v.z); o.w = f2bf(v.w);
  *(ushort4*)(X + m * LDX + c4) = o;
}

// ---------- KNN top-2 + local covariance -> X cols 512..543
// grid (N/64, B), 256 threads. Each wave: 16 points x 4 j-slices.
__global__ __launch_bounds__(256) void knn_kernel(const float* __restrict__ rp,
                                                  unsigned short* __restrict__ X) {
  __shared__ float4 P[NPTS];  // x,y,z,|p|^2  (64 KB)
  int b = blockIdx.y;
  const float* base = rp + (size_t)b * 3 * NPTS;
  for (int j = threadIdx.x; j < NPTS; j += 256) {
    float x = base[j], y = base[NPTS + j], z = base[2 * NPTS + j];
    float xx = __fadd_rn(__fadd_rn(__fmul_rn(x, x), __fmul_rn(y, y)), __fmul_rn(z, z));
    P[j] = make_float4(x, y, z, xx);
  }
  __syncthreads();
  int wave = threadIdx.x >> 6, lane = threadIdx.x & 63;
  int il = wave * 16 + (lane >> 2);   // local point 0..63
  int slice = lane & 3;               // j-slice
  int i = blockIdx.x * 64 + il;
  float4 pi = P[i];
  float v1 = -3.4e38f, v2 = -3.4e38f;
  int i1 = 0x7fffffff, i2 = 0x7fffffff;
  int jb = slice * (NPTS / 4), je = jb + (NPTS / 4);
  for (int j = jb; j < je; ++j) {
    float4 pj = P[j];
    float inner = __fadd_rn(__fadd_rn(__fmul_rn(pi.x, pj.x), __fmul_rn(pi.y, pj.y)),
                            __fmul_rn(pi.z, pj.z));
    // matches reference: (-xx_i + 2*inner) - xx_j, no contraction
    float d = __fsub_rn(__fadd_rn(-pi.w, __fmul_rn(2.0f, inner)), pj.w);
    if (d > v1) { v2 = v1; i2 = i1; v1 = d; i1 = j; }
    else if (d > v2) { v2 = d; i2 = j; }
  }
  // merge the 4 slices (lanes xor 1, then xor 2); tie -> lower index
#pragma unroll
  for (int mk = 1; mk <= 2; mk <<= 1) {
    float ov1 = __shfl_xor(v1, mk); int oi1 = __shfl_xor(i1, mk);
    float ov2 = __shfl_xor(v2, mk); int oi2 = __shfl_xor(i2, mk);
    bool ofirst = (ov1 > v1) || (ov1 == v1 && oi1 < i1);
    float n1v, n2v; int n1i, n2i;
    if (ofirst) {
      n1v = ov1; n1i = oi1;
      bool t = (v1 > ov2) || (v1 == ov2 && i1 < oi2);
      n2v = t ? v1 : ov2; n2i = t ? i1 : oi2;
    } else {
      n1v = v1; n1i = i1;
      bool t = (ov1 > v2) || (ov1 == v2 && oi1 < i2);
      n2v = t ? ov1 : v2; n2i = t ? oi1 : i2;
    }
    v1 = n1v; i1 = n1i; v2 = n2v; i2 = n2i;
  }
  if (slice == 0) {
    float4 p0 = P[i1];   // nearest (self)
    float4 p1 = P[i2];   // 2nd nearest
    size_t row = (size_t)b * NPTS + blockIdx.x * 64 + il;
    unsigned short* xp = X + row * LDX + 512;
    float vals[12] = { pi.x, pi.y, pi.z,
                       p0.x * p1.x, p0.x * p1.y, p0.x * p1.z,
                       p0.y * p1.x, p0.y * p1.y, p0.y * p1.z,
                       p0.z * p1.x, p0.z * p1.y, p0.z * p1.z };
#pragma unroll
    for (int k = 0; k < 12; ++k) xp[k] = f2bf(vals[k]);
#pragma unroll
    for (int k = 12; k < 32; ++k) xp[k] = 0;   // zero pad cols 524..543
  }
}

// ---------- GEMM1: H = relu(X @ W + b)   X:[M][ldx] bf16, Wt:[512][ldw] bf16 (n-major)
#define BM 128
#define BN 128
#define BK 32
__global__ __launch_bounds__(256) void gemm_relu_kernel(
    const unsigned short* __restrict__ Xb, const unsigned short* __restrict__ Wt,
    const float* __restrict__ bias, unsigned short* __restrict__ H,
    int K, int ldx, int ldw) {
  __shared__ unsigned short As[BM * BK];
  __shared__ unsigned short Bs[BN * BK];
  const int t = threadIdx.x;
  const int wave = t >> 6, lane = t & 63;
  const int m0 = blockIdx.y * BM, n0 = blockIdx.x * BN;
  const int wm = (wave >> 1) * 64, wn = (wave & 1) * 64;
  const int sr = lane >> 2;          // row within 16-row chunk
  const int sc = (lane & 3) * 8;     // k-element offset (16B)
  const int q = lane >> 4, lm = lane & 15;
  f32x4 acc[4][4] = {};
  for (int kt = 0; kt < K; kt += BK) {
#pragma unroll
    for (int r = 0; r < 2; ++r) {
      int c = r * 4 + wave;
      gload_lds16(Xb + (size_t)(m0 + c * 16 + sr) * ldx + kt + sc, As + c * 512);
    }
#pragma unroll
    for (int r = 0; r < 2; ++r) {
      int c = r * 4 + wave;
      gload_lds16(Wt + (size_t)(n0 + c * 16 + sr) * ldw + kt + sc, Bs + c * 512);
    }
    __syncthreads();
    bf16x8 a[4], bfr[4];
#pragma unroll
    for (int i = 0; i < 4; ++i)
      a[i] = *(const bf16x8*)(As + (wm + i * 16 + lm) * BK + q * 8);
#pragma unroll
    for (int j = 0; j < 4; ++j)
      bfr[j] = *(const bf16x8*)(Bs + (wn + j * 16 + lm) * BK + q * 8);
#pragma unroll
    for (int i = 0; i < 4; ++i)
#pragma unroll
      for (int j = 0; j < 4; ++j)
        acc[i][j] = __builtin_amdgcn_mfma_f32_16x16x32_bf16(a[i], bfr[j], acc[i][j], 0, 0, 0);
    __syncthreads();
  }
#pragma unroll
  for (int i = 0; i < 4; ++i)
#pragma unroll
    for (int j = 0; j < 4; ++j) {
      int col = n0 + wn + j * 16 + lm;
      float bv = bias[col];
#pragma unroll
      for (int rg = 0; rg < 4; ++rg) {
        int row = m0 + wm + i * 16 + q * 4 + rg;
        float v = acc[i][j][rg] + bv;
        v = v > 0.f ? v : 0.f;
        H[(size_t)row * 512 + col] = f2bf(v);
      }
    }
}

// ---------- GEMM2: h2 = relu(H1 + H1@Wr + br); stage_out[row] += h2 . w2  (atomic)
__global__ __launch_bounds__(256) void gemm_res_kernel(
    const unsigned short* __restrict__ H1, const unsigned short* __restrict__ Wt,
    const float* __restrict__ br, const float* __restrict__ w2,
    float* __restrict__ so) {
  __shared__ unsigned short As[BM * BK];
  __shared__ unsigned short Bs[BN * BK];
  const int t = threadIdx.x;
  const int wave = t >> 6, lane = t & 63;
  const int m0 = blockIdx.y * BM, n0 = blockIdx.x * BN;
  const int wm = (wave >> 1) * 64, wn = (wave & 1) * 64;
  const int sr = lane >> 2, sc = (lane & 3) * 8;
  const int q = lane >> 4, lm = lane & 15;
  f32x4 acc[4][4] = {};
  for (int kt = 0; kt < 512; kt += BK) {
#pragma unroll
    for (int r = 0; r < 2; ++r) {
      int c = r * 4 + wave;
      gload_lds16(H1 + (size_t)(m0 + c * 16 + sr) * 512 + kt + sc, As + c * 512);
    }
#pragma unroll
    for (int r = 0; r < 2; ++r) {
      int c = r * 4 + wave;
      gload_lds16(Wt + (size_t)(n0 + c * 16 + sr) * 512 + kt + sc, Bs + c * 512);
    }
    __syncthreads();
    bf16x8 a[4], bfr[4];
#pragma unroll
    for (int i = 0; i < 4; ++i)
      a[i] = *(const bf16x8*)(As + (wm + i * 16 + lm) * BK + q * 8);
#pragma unroll
    for (int j = 0; j < 4; ++j)
      bfr[j] = *(const bf16x8*)(Bs + (wn + j * 16 + lm) * BK + q * 8);
#pragma unroll
    for (int i = 0; i < 4; ++i)
#pragma unroll
      for (int j = 0; j < 4; ++j)
        acc[i][j] = __builtin_amdgcn_mfma_f32_16x16x32_bf16(a[i], bfr[j], acc[i][j], 0, 0, 0);
    __syncthreads();
  }
  float partial[4][4];
#pragma unroll
  for (int i = 0; i < 4; ++i)
#pragma unroll
    for (int rg = 0; rg < 4; ++rg) partial[i][rg] = 0.f;
#pragma unroll
  for (int i = 0; i < 4; ++i)
#pragma unroll
    for (int j = 0; j < 4; ++j) {
      int col = n0 + wn + j * 16 + lm;
      float bv = br[col], wv = w2[col];
#pragma unroll
      for (int rg = 0; rg < 4; ++rg) {
        int row = m0 + wm + i * 16 + q * 4 + rg;
        float h1 = bf2f(H1[(size_t)row * 512 + col]);
        float v = h1 + acc[i][j][rg] + bv;
        v = v > 0.f ? v : 0.f;
        partial[i][rg] += v * wv;
      }
    }
#pragma unroll
  for (int i = 0; i < 4; ++i)
#pragma unroll
    for (int rg = 0; rg < 4; ++rg) {
      float s = partial[i][rg];
      s += __shfl_xor(s, 1); s += __shfl_xor(s, 2);
      s += __shfl_xor(s, 4); s += __shfl_xor(s, 8);
      if (lm == 0) atomicAdd(&so[m0 + wm + i * 16 + q * 4 + rg], s);
    }
}

// ---------- small kernels ----------
__global__ __launch_bounds__(256) void init_so_kernel(float* so, const float* b2) {
  int m = blockIdx.x * 256 + threadIdx.x;
  so[m] = b2[0];
}
__global__ __launch_bounds__(256) void update_kernel(float* std_cum, float* so,
                                                     unsigned short* X,
                                                     const float* b2_next, int first) {
  int m = blockIdx.x * 256 + threadIdx.x;
  float s = so[m];
  if (!first) s += std_cum[m];
  std_cum[m] = s;
  unsigned short* xp = X + (size_t)m * LDX + 512;
  xp[0] = f2bf(s);
#pragma unroll
  for (int k = 1; k < 12; ++k) xp[k] = 0;
  so[m] = b2_next[0];
}
__global__ __launch_bounds__(256) void finalize_kernel(float* out, const float* std_cum,
                                                       const float* so) {
  int m = blockIdx.x * 256 + threadIdx.x;
  out[m] = std_cum[m] + so[m];
}

extern "C" void kernel_launch(void* const* d_in, const int* in_sizes, int n_in,
                              void* d_out, int out_size, void* d_ws, size_t ws_size,
                              hipStream_t stream) {
  const int B = 8, N = NPTS, M = B * N;
  const float* latent = (const float*)d_in[0];
  const float* rp = (const float*)d_in[1];
  const float* w1[3] = {(const float*)d_in[2], (const float*)d_in[8], (const float*)d_in[14]};
  const float* b1[3] = {(const float*)d_in[3], (const float*)d_in[9], (const float*)d_in[15]};
  const float* wr[3] = {(const float*)d_in[4], (const float*)d_in[10], (const float*)d_in[16]};
  const float* br[3] = {(const float*)d_in[5], (const float*)d_in[11], (const float*)d_in[17]};
  const float* w2[3] = {(const float*)d_in[6], (const float*)d_in[12], (const float*)d_in[18]};
  const float* b2[3] = {(const float*)d_in[7], (const float*)d_in[13], (const float*)d_in[19]};

  char* ws = (char*)d_ws;
  auto carve = [&](size_t bytes) {
    char* p = ws;
    ws += (bytes + 255) & ~(size_t)255;
    return p;
  };
  unsigned short* X  = (unsigned short*)carve((size_t)M * LDX * 2);
  unsigned short* H1 = (unsigned short*)carve((size_t)M * 512 * 2);
  unsigned short* W1t[3], *Wrt[3];
  for (int s = 0; s < 3; ++s) W1t[s] = (unsigned short*)carve((size_t)512 * LDX * 2);
  for (int s = 0; s < 3; ++s) Wrt[s] = (unsigned short*)carve((size_t)512 * 512 * 2);
  float* std_cum = (float*)carve((size_t)M * 4);
  float* so      = (float*)carve((size_t)M * 4);

  // weights -> bf16 transposed [n][k]
  for (int s = 0; s < 3; ++s) {
    int Ksrc = (s == 0) ? 524 : 513;
    convw_kernel<<<dim3(LDX / 32, 16), 256, 0, stream>>>(w1[s], W1t[s], Ksrc, LDX);
    convw_kernel<<<dim3(16, 16), 256, 0, stream>>>(wr[s], Wrt[s], 512, 512);
  }
  // latent -> X[:,0:512]
  conv_latent_kernel<<<(M * 128) / 256, 256, 0, stream>>>(latent, X);
  // knn + cov -> X[:,512:544]
  knn_kernel<<<dim3(N / 64, B), 256, 0, stream>>>(rp, X);
  init_so_kernel<<<M / 256, 256, 0, stream>>>(so, b2[0]);

  for (int s = 0; s < 3; ++s) {
    gemm_relu_kernel<<<dim3(4, M / BM), 256, 0, stream>>>(X, W1t[s], b1[s], H1, LDX, LDX, LDX);
    gemm_res_kernel<<<dim3(4, M / BM), 256, 0, stream>>>(H1, Wrt[s], br[s], w2[s], so);
    if (s < 2)
      update_kernel<<<M / 256, 256, 0, stream>>>(std_cum, so, X, b2[s + 1], s == 0 ? 1 : 0);
  }
  finalize_kernel<<<M / 256, 256, 0, stream>>>((float*)d_out, std_cum, so);
}

// Round 2
// 432.062 us; speedup vs baseline: 1.1055x; 1.1055x over previous
//
#include <hip/hip_runtime.h>

// ---------- helpers ----------
typedef __bf16 bf16x8 __attribute__((ext_vector_type(8)));
typedef float f32x4 __attribute__((ext_vector_type(4)));

__device__ __forceinline__ unsigned short f2bf(float f) {
  unsigned u = __float_as_uint(f);
  u += 0x7FFFu + ((u >> 16) & 1u);   // RNE
  return (unsigned short)(u >> 16);
}
__device__ __forceinline__ float bf2f(unsigned short h) {
  return __uint_as_float(((unsigned)h) << 16);
}

__device__ __forceinline__ void gload_lds16(const void* g, void* l) {
  __builtin_amdgcn_global_load_lds((const __attribute__((address_space(1))) void*)g,
                                   (__attribute__((address_space(3))) void*)l,
                                   16, 0, 0);
}

#define NPTS 4096
#define LDX 544   // padded K for stage GEMM1 (524->544, 513->544)

// ---------- weight transpose + bf16 convert: src fp32 [Ksrc][512] -> dst u16 [512][Kpad]
__global__ __launch_bounds__(256) void convw_kernel(const float* __restrict__ src,
                                                    unsigned short* __restrict__ dst,
                                                    int Ksrc, int Kpad) {
  __shared__ float tile[32][33];
  int k0 = blockIdx.x * 32, n0 = blockIdx.y * 32;
  int tx = threadIdx.x & 31, ty = threadIdx.x >> 5;  // 32 x 8
#pragma unroll
  for (int r = 0; r < 32; r += 8) {
    int k = k0 + ty + r, n = n0 + tx;
    tile[ty + r][tx] = (k < Ksrc) ? src[(size_t)k * 512 + n] : 0.f;
  }
  __syncthreads();
#pragma unroll
  for (int r = 0; r < 32; r += 8) {
    int n = n0 + ty + r, k = k0 + tx;
    dst[(size_t)n * Kpad + k] = f2bf(tile[tx][ty + r]);
  }
}

// ---------- latent fp32 [M][512] -> X bf16 cols 0..511 (row stride LDX)
__global__ __launch_bounds__(256) void conv_latent_kernel(const float* __restrict__ latent,
                                                          unsigned short* __restrict__ X) {
  size_t idx = (size_t)blockIdx.x * 256 + threadIdx.x;  // over M*128 float4 groups
  size_t m = idx >> 7;
  int c4 = (int)(idx & 127) * 4;
  float4 v = *(const float4*)(latent + m * 512 + c4);
  ushort4 o;
  o.x = f2bf(v.x); o.y = f2bf(v.y); o.z = f2bf(v.z); o.w = f2bf(v.w);
  *(ushort4*)(X + m * LDX + c4) = o;
}

// ---------- KNN top-2 + local covariance -> X cols 512..543
// grid (N/64, B), 512 threads. Per wave: 4 duos (2 points each) x 16 j-slices.
// Slice s scans j == s (mod 16)  -> wave's 16 unique LDS addrs are 256B contiguous
// (conflict-free, broadcast across the 4 duos).
__device__ __forceinline__ void merge2(float& v1, int& i1, float& v2, int& i2, int mk) {
  float ov1 = __shfl_xor(v1, mk); int oi1 = __shfl_xor(i1, mk);
  float ov2 = __shfl_xor(v2, mk); int oi2 = __shfl_xor(i2, mk);
  bool ofirst = (ov1 > v1) || (ov1 == v1 && oi1 < i1);
  float n1v, n2v; int n1i, n2i;
  if (ofirst) {
    n1v = ov1; n1i = oi1;
    bool t = (v1 > ov2) || (v1 == ov2 && i1 < oi2);
    n2v = t ? v1 : ov2; n2i = t ? i1 : oi2;
  } else {
    n1v = v1; n1i = i1;
    bool t = (ov1 > v2) || (ov1 == v2 && oi1 < i2);
    n2v = t ? ov1 : v2; n2i = t ? oi1 : i2;
  }
  v1 = n1v; i1 = n1i; v2 = n2v; i2 = n2i;
}

__global__ __launch_bounds__(512) void knn_kernel(const float* __restrict__ rp,
                                                  unsigned short* __restrict__ X) {
  __shared__ float4 P[NPTS];  // x,y,z,|p|^2  (64 KB)
  int b = blockIdx.y;
  const float* base = rp + (size_t)b * 3 * NPTS;
  for (int j = threadIdx.x; j < NPTS; j += 512) {
    float x = base[j], y = base[NPTS + j], z = base[2 * NPTS + j];
    float xx = __fadd_rn(__fadd_rn(__fmul_rn(x, x), __fmul_rn(y, y)), __fmul_rn(z, z));
    P[j] = make_float4(x, y, z, xx);
  }
  __syncthreads();
  int wave = threadIdx.x >> 6, lane = threadIdx.x & 63;
  int duo = lane >> 4, slice = lane & 15;
  int il0 = wave * 8 + duo * 2;          // this lane's two points: il0, il0+1
  int ia = blockIdx.x * 64 + il0;
  float4 pa = P[ia];
  float4 pb = P[ia + 1];
  float av1 = -3.4e38f, av2 = -3.4e38f, bv1 = -3.4e38f, bv2 = -3.4e38f;
  int ai1 = 0x7fffffff, ai2 = 0x7fffffff, bi1 = 0x7fffffff, bi2 = 0x7fffffff;
#pragma unroll 4
  for (int t = 0; t < NPTS / 16; ++t) {
    int j = t * 16 + slice;
    float4 pj = P[j];
    // exact reference ordering: inner = x*x' + y*y' + z*z'; d = (-xx_i + 2*inner) - xx_j
    float ina = __fadd_rn(__fadd_rn(__fmul_rn(pa.x, pj.x), __fmul_rn(pa.y, pj.y)),
                          __fmul_rn(pa.z, pj.z));
    float da = __fsub_rn(__fadd_rn(-pa.w, __fmul_rn(2.0f, ina)), pj.w);
    if (da > av1)      { av2 = av1; ai2 = ai1; av1 = da; ai1 = j; }
    else if (da > av2) { av2 = da; ai2 = j; }
    float inb = __fadd_rn(__fadd_rn(__fmul_rn(pb.x, pj.x), __fmul_rn(pb.y, pj.y)),
                          __fmul_rn(pb.z, pj.z));
    float db = __fsub_rn(__fadd_rn(-pb.w, __fmul_rn(2.0f, inb)), pj.w);
    if (db > bv1)      { bv2 = bv1; bi2 = bi1; bv1 = db; bi1 = j; }
    else if (db > bv2) { bv2 = db; bi2 = j; }
  }
  // merge the 16 slices (xor 1,2,4,8 stays within the duo's 16-lane group)
#pragma unroll
  for (int mk = 1; mk <= 8; mk <<= 1) {
    merge2(av1, ai1, av2, ai2, mk);
    merge2(bv1, bi1, bv2, bi2, mk);
  }
  if (slice == 0) {
#pragma unroll
    for (int p = 0; p < 2; ++p) {
      int i = ia + p;
      float4 pi = (p == 0) ? pa : pb;
      int j1 = (p == 0) ? ai1 : bi1;
      int j2 = (p == 0) ? ai2 : bi2;
      float4 p0 = P[j1];   // nearest (self)
      float4 p1 = P[j2];   // 2nd nearest
      size_t row = (size_t)b * NPTS + i;
      unsigned short* xp = X + row * LDX + 512;
      float vals[12] = { pi.x, pi.y, pi.z,
                         p0.x * p1.x, p0.x * p1.y, p0.x * p1.z,
                         p0.y * p1.x, p0.y * p1.y, p0.y * p1.z,
                         p0.z * p1.x, p0.z * p1.y, p0.z * p1.z };
#pragma unroll
      for (int k = 0; k < 12; ++k) xp[k] = f2bf(vals[k]);
#pragma unroll
      for (int k = 12; k < 32; ++k) xp[k] = 0;   // zero pad cols 524..543
    }
  }
}

// ---------- GEMM1: H = relu(X @ W + b)   X:[M][ldx] bf16, Wt:[512][ldw] bf16 (n-major)
#define BM 128
#define BN 128
#define BK 32
__global__ __launch_bounds__(256) void gemm_relu_kernel(
    const unsigned short* __restrict__ Xb, const unsigned short* __restrict__ Wt,
    const float* __restrict__ bias, unsigned short* __restrict__ H,
    int K, int ldx, int ldw) {
  __shared__ unsigned short As[BM * BK];
  __shared__ unsigned short Bs[BN * BK];
  const int t = threadIdx.x;
  const int wave = t >> 6, lane = t & 63;
  const int m0 = blockIdx.y * BM, n0 = blockIdx.x * BN;
  const int wm = (wave >> 1) * 64, wn = (wave & 1) * 64;
  const int sr = lane >> 2;          // row within 16-row chunk
  const int sc = (lane & 3) * 8;     // k-element offset (16B)
  const int q = lane >> 4, lm = lane & 15;
  f32x4 acc[4][4] = {};
  for (int kt = 0; kt < K; kt += BK) {
#pragma unroll
    for (int r = 0; r < 2; ++r) {
      int c = r * 4 + wave;
      gload_lds16(Xb + (size_t)(m0 + c * 16 + sr) * ldx + kt + sc, As + c * 512);
    }
#pragma unroll
    for (int r = 0; r < 2; ++r) {
      int c = r * 4 + wave;
      gload_lds16(Wt + (size_t)(n0 + c * 16 + sr) * ldw + kt + sc, Bs + c * 512);
    }
    __syncthreads();
    bf16x8 a[4], bfr[4];
#pragma unroll
    for (int i = 0; i < 4; ++i)
      a[i] = *(const bf16x8*)(As + (wm + i * 16 + lm) * BK + q * 8);
#pragma unroll
    for (int j = 0; j < 4; ++j)
      bfr[j] = *(const bf16x8*)(Bs + (wn + j * 16 + lm) * BK + q * 8);
#pragma unroll
    for (int i = 0; i < 4; ++i)
#pragma unroll
      for (int j = 0; j < 4; ++j)
        acc[i][j] = __builtin_amdgcn_mfma_f32_16x16x32_bf16(a[i], bfr[j], acc[i][j], 0, 0, 0);
    __syncthreads();
  }
#pragma unroll
  for (int i = 0; i < 4; ++i)
#pragma unroll
    for (int j = 0; j < 4; ++j) {
      int col = n0 + wn + j * 16 + lm;
      float bv = bias[col];
#pragma unroll
      for (int rg = 0; rg < 4; ++rg) {
        int row = m0 + wm + i * 16 + q * 4 + rg;
        float v = acc[i][j][rg] + bv;
        v = v > 0.f ? v : 0.f;
        H[(size_t)row * 512 + col] = f2bf(v);
      }
    }
}

// ---------- GEMM2: h2 = relu(H1 + H1@Wr + br); stage_out[row] += h2 . w2  (atomic)
__global__ __launch_bounds__(256) void gemm_res_kernel(
    const unsigned short* __restrict__ H1, const unsigned short* __restrict__ Wt,
    const float* __restrict__ br, const float* __restrict__ w2,
    float* __restrict__ so) {
  __shared__ unsigned short As[BM * BK];
  __shared__ unsigned short Bs[BN * BK];
  const int t = threadIdx.x;
  const int wave = t >> 6, lane = t & 63;
  const int m0 = blockIdx.y * BM, n0 = blockIdx.x * BN;
  const int wm = (wave >> 1) * 64, wn = (wave & 1) * 64;
  const int sr = lane >> 2, sc = (lane & 3) * 8;
  const int q = lane >> 4, lm = lane & 15;
  f32x4 acc[4][4] = {};
  for (int kt = 0; kt < 512; kt += BK) {
#pragma unroll
    for (int r = 0; r < 2; ++r) {
      int c = r * 4 + wave;
      gload_lds16(H1 + (size_t)(m0 + c * 16 + sr) * 512 + kt + sc, As + c * 512);
    }
#pragma unroll
    for (int r = 0; r < 2; ++r) {
      int c = r * 4 + wave;
      gload_lds16(Wt + (size_t)(n0 + c * 16 + sr) * 512 + kt + sc, Bs + c * 512);
    }
    __syncthreads();
    bf16x8 a[4], bfr[4];
#pragma unroll
    for (int i = 0; i < 4; ++i)
      a[i] = *(const bf16x8*)(As + (wm + i * 16 + lm) * BK + q * 8);
#pragma unroll
    for (int j = 0; j < 4; ++j)
      bfr[j] = *(const bf16x8*)(Bs + (wn + j * 16 + lm) * BK + q * 8);
#pragma unroll
    for (int i = 0; i < 4; ++i)
#pragma unroll
      for (int j = 0; j < 4; ++j)
        acc[i][j] = __builtin_amdgcn_mfma_f32_16x16x32_bf16(a[i], bfr[j], acc[i][j], 0, 0, 0);
    __syncthreads();
  }
  float partial[4][4];
#pragma unroll
  for (int i = 0; i < 4; ++i)
#pragma unroll
    for (int rg = 0; rg < 4; ++rg) partial[i][rg] = 0.f;
#pragma unroll
  for (int i = 0; i < 4; ++i)
#pragma unroll
    for (int j = 0; j < 4; ++j) {
      int col = n0 + wn + j * 16 + lm;
      float bv = br[col], wv = w2[col];
#pragma unroll
      for (int rg = 0; rg < 4; ++rg) {
        int row = m0 + wm + i * 16 + q * 4 + rg;
        float h1 = bf2f(H1[(size_t)row * 512 + col]);
        float v = h1 + acc[i][j][rg] + bv;
        v = v > 0.f ? v : 0.f;
        partial[i][rg] += v * wv;
      }
    }
#pragma unroll
  for (int i = 0; i < 4; ++i)
#pragma unroll
    for (int rg = 0; rg < 4; ++rg) {
      float s = partial[i][rg];
      s += __shfl_xor(s, 1); s += __shfl_xor(s, 2);
      s += __shfl_xor(s, 4); s += __shfl_xor(s, 8);
      if (lm == 0) atomicAdd(&so[m0 + wm + i * 16 + q * 4 + rg], s);
    }
}

// ---------- small kernels ----------
__global__ __launch_bounds__(256) void init_so_kernel(float* so, const float* b2) {
  int m = blockIdx.x * 256 + threadIdx.x;
  so[m] = b2[0];
}
__global__ __launch_bounds__(256) void update_kernel(float* std_cum, float* so,
                                                     unsigned short* X,
                                                     const float* b2_next, int first) {
  int m = blockIdx.x * 256 + threadIdx.x;
  float s = so[m];
  if (!first) s += std_cum[m];
  std_cum[m] = s;
  unsigned short* xp = X + (size_t)m * LDX + 512;
  xp[0] = f2bf(s);
#pragma unroll
  for (int k = 1; k < 12; ++k) xp[k] = 0;
  so[m] = b2_next[0];
}
__global__ __launch_bounds__(256) void finalize_kernel(float* out, const float* std_cum,
                                                       const float* so) {
  int m = blockIdx.x * 256 + threadIdx.x;
  out[m] = std_cum[m] + so[m];
}

extern "C" void kernel_launch(void* const* d_in, const int* in_sizes, int n_in,
                              void* d_out, int out_size, void* d_ws, size_t ws_size,
                              hipStream_t stream) {
  const int B = 8, N = NPTS, M = B * N;
  const float* latent = (const float*)d_in[0];
  const float* rp = (const float*)d_in[1];
  const float* w1[3] = {(const float*)d_in[2], (const float*)d_in[8], (const float*)d_in[14]};
  const float* b1[3] = {(const float*)d_in[3], (const float*)d_in[9], (const float*)d_in[15]};
  const float* wr[3] = {(const float*)d_in[4], (const float*)d_in[10], (const float*)d_in[16]};
  const float* br[3] = {(const float*)d_in[5], (const float*)d_in[11], (const float*)d_in[17]};
  const float* w2[3] = {(const float*)d_in[6], (const float*)d_in[12], (const float*)d_in[18]};
  const float* b2[3] = {(const float*)d_in[7], (const float*)d_in[13], (const float*)d_in[19]};

  char* ws = (char*)d_ws;
  auto carve = [&](size_t bytes) {
    char* p = ws;
    ws += (bytes + 255) & ~(size_t)255;
    return p;
  };
  unsigned short* X  = (unsigned short*)carve((size_t)M * LDX * 2);
  unsigned short* H1 = (unsigned short*)carve((size_t)M * 512 * 2);
  unsigned short* W1t[3], *Wrt[3];
  for (int s = 0; s < 3; ++s) W1t[s] = (unsigned short*)carve((size_t)512 * LDX * 2);
  for (int s = 0; s < 3; ++s) Wrt[s] = (unsigned short*)carve((size_t)512 * 512 * 2);
  float* std_cum = (float*)carve((size_t)M * 4);
  float* so      = (float*)carve((size_t)M * 4);

  // weights -> bf16 transposed [n][k]
  for (int s = 0; s < 3; ++s) {
    int Ksrc = (s == 0) ? 524 : 513;
    convw_kernel<<<dim3(LDX / 32, 16), 256, 0, stream>>>(w1[s], W1t[s], Ksrc, LDX);
    convw_kernel<<<dim3(16, 16), 256, 0, stream>>>(wr[s], Wrt[s], 512, 512);
  }
  // latent -> X[:,0:512]
  conv_latent_kernel<<<(M * 128) / 256, 256, 0, stream>>>(latent, X);
  // knn + cov -> X[:,512:544]
  knn_kernel<<<dim3(N / 64, B), 512, 0, stream>>>(rp, X);
  init_so_kernel<<<M / 256, 256, 0, stream>>>(so, b2[0]);

  for (int s = 0; s < 3; ++s) {
    gemm_relu_kernel<<<dim3(4, M / BM), 256, 0, stream>>>(X, W1t[s], b1[s], H1, LDX, LDX, LDX);
    gemm_res_kernel<<<dim3(4, M / BM), 256, 0, stream>>>(H1, Wrt[s], br[s], w2[s], so);
    if (s < 2)
      update_kernel<<<M / 256, 256, 0, stream>>>(std_cum, so, X, b2[s + 1], s == 0 ? 1 : 0);
  }
  finalize_kernel<<<M / 256, 256, 0, stream>>>((float*)d_out, std_cum, so);
}

// Round 3
// 400.024 us; speedup vs baseline: 1.1941x; 1.0801x over previous
//
#include <hip/hip_runtime.h>

// ---------- helpers ----------
typedef __bf16 bf16x8 __attribute__((ext_vector_type(8)));
typedef float f32x4 __attribute__((ext_vector_type(4)));

__device__ __forceinline__ unsigned short f2bf(float f) {
  unsigned u = __float_as_uint(f);
  u += 0x7FFFu + ((u >> 16) & 1u);   // RNE
  return (unsigned short)(u >> 16);
}

__device__ __forceinline__ void gload_lds16(const void* g, void* l) {
  __builtin_amdgcn_global_load_lds((const __attribute__((address_space(1))) void*)g,
                                   (__attribute__((address_space(3))) void*)l,
                                   16, 0, 0);
}

#define NPTS 4096
#define LDX 576   // padded K for stage GEMM1, divisible by BK=64

// ---------- batched weight transpose+convert: 6 weights in one launch
// z<3: w1[z] fp32 [Ksrc][512] -> W1t bf16 [512][576]; z>=3: wr -> Wrt [512][512] with +I
__global__ __launch_bounds__(256) void convw6_kernel(
    const float* w0, const float* w1, const float* w2,
    const float* r0, const float* r1, const float* r2,
    unsigned short* d0, unsigned short* d1, unsigned short* d2,
    unsigned short* e0, unsigned short* e1, unsigned short* e2) {
  int z = blockIdx.z;
  const float* src; unsigned short* dst; int Ksrc, Kpad, addI;
  switch (z) {
    case 0: src = w0; dst = d0; Ksrc = 524; Kpad = 576; addI = 0; break;
    case 1: src = w1; dst = d1; Ksrc = 513; Kpad = 576; addI = 0; break;
    case 2: src = w2; dst = d2; Ksrc = 513; Kpad = 576; addI = 0; break;
    case 3: src = r0; dst = e0; Ksrc = 512; Kpad = 512; addI = 1; break;
    case 4: src = r1; dst = e1; Ksrc = 512; Kpad = 512; addI = 1; break;
    default: src = r2; dst = e2; Ksrc = 512; Kpad = 512; addI = 1; break;
  }
  int k0 = blockIdx.x * 32;
  if (k0 >= Kpad) return;
  __shared__ float tile[32][33];
  int n0 = blockIdx.y * 32;
  int tx = threadIdx.x & 31, ty = threadIdx.x >> 5;  // 32 x 8
#pragma unroll
  for (int r = 0; r < 32; r += 8) {
    int k = k0 + ty + r, n = n0 + tx;
    tile[ty + r][tx] = (k < Ksrc) ? src[(size_t)k * 512 + n] : 0.f;
  }
  __syncthreads();
#pragma unroll
  for (int r = 0; r < 32; r += 8) {
    int n = n0 + ty + r, k = k0 + tx;
    float v = tile[tx][ty + r];
    if (addI && n == k) v += 1.0f;   // fold residual identity into Wr
    dst[(size_t)n * Kpad + k] = f2bf(v);
  }
}

// ---------- latent fp32 [M][512] -> X bf16 cols 0..511 (row stride LDX)
__global__ __launch_bounds__(256) void conv_latent_kernel(const float* __restrict__ latent,
                                                          unsigned short* __restrict__ X) {
  size_t idx = (size_t)blockIdx.x * 256 + threadIdx.x;  // over M*128 float4 groups
  size_t m = idx >> 7;
  int c4 = (int)(idx & 127) * 4;
  float4 v = *(const float4*)(latent + m * 512 + c4);
  ushort4 o;
  o.x = f2bf(v.x); o.y = f2bf(v.y); o.z = f2bf(v.z); o.w = f2bf(v.w);
  *(ushort4*)(X + m * LDX + c4) = o;
}

// ---------- KNN top-2 + local covariance -> X cols 512..543
// grid (N/128, B), 512 threads. Per 16-lane group: 4 points; slice s scans j==s (mod 16)
// -> conflict-free 256B-contiguous LDS reads broadcast across groups.
// fp32 FMA is licensed: np reference einsum uses BLAS op order != our sequential order
// anyway, and we pass at pure-bf16-noise absmax; fp32 reorder noise (~1e-7 rel) is far
// below rank-2/3 distance gaps. bf16 distances would NOT be safe.
__device__ __forceinline__ void merge2(float& v1, int& i1, float& v2, int& i2, int mk) {
  float ov1 = __shfl_xor(v1, mk); int oi1 = __shfl_xor(i1, mk);
  float ov2 = __shfl_xor(v2, mk); int oi2 = __shfl_xor(i2, mk);
  bool ofirst = (ov1 > v1) || (ov1 == v1 && oi1 < i1);
  float n1v, n2v; int n1i, n2i;
  if (ofirst) {
    n1v = ov1; n1i = oi1;
    bool t = (v1 > ov2) || (v1 == ov2 && i1 < oi2);
    n2v = t ? v1 : ov2; n2i = t ? i1 : oi2;
  } else {
    n1v = v1; n1i = i1;
    bool t = (ov1 > v2) || (ov1 == v2 && oi1 < i2);
    n2v = t ? ov1 : v2; n2i = t ? oi1 : i2;
  }
  v1 = n1v; i1 = n1i; v2 = n2v; i2 = n2i;
}

__global__ __launch_bounds__(512) void knn_kernel(const float* __restrict__ rp,
                                                  unsigned short* __restrict__ X) {
  __shared__ float4 P[NPTS];  // x,y,z,|p|^2  (64 KB)
  int b = blockIdx.y;
  const float* base = rp + (size_t)b * 3 * NPTS;
  for (int j = threadIdx.x; j < NPTS; j += 512) {
    float x = base[j], y = base[NPTS + j], z = base[2 * NPTS + j];
    float xx = __fadd_rn(__fadd_rn(__fmul_rn(x, x), __fmul_rn(y, y)), __fmul_rn(z, z));
    P[j] = make_float4(x, y, z, xx);
  }
  __syncthreads();
  int wave = threadIdx.x >> 6, lane = threadIdx.x & 63;
  int grp = lane >> 4, slice = lane & 15;
  int il0 = wave * 16 + grp * 4;         // this group's 4 points
  int ibase = blockIdx.x * 128 + il0;
  float tx[4], ty[4], tz[4], tc[4];
  float v1[4], v2[4]; int i1[4], i2[4];
#pragma unroll
  for (int p = 0; p < 4; ++p) {
    float4 pp = P[ibase + p];
    tx[p] = 2.f * pp.x; ty[p] = 2.f * pp.y; tz[p] = 2.f * pp.z; tc[p] = -pp.w;
    v1[p] = -3.4e38f; v2[p] = -3.4e38f; i1[p] = 0x7fffffff; i2[p] = 0x7fffffff;
  }
#pragma unroll 4
  for (int t = 0; t < NPTS / 16; ++t) {
    int j = t * 16 + slice;
    float4 pj = P[j];
#pragma unroll
    for (int p = 0; p < 4; ++p) {
      float d = __builtin_fmaf(tx[p], pj.x,
                __builtin_fmaf(ty[p], pj.y,
                __builtin_fmaf(tz[p], pj.z, tc[p]))) - pj.w;
      bool c1 = d > v1[p];
      bool c2 = d > v2[p];
      i2[p] = c1 ? i1[p] : (c2 ? j : i2[p]);
      v2[p] = __builtin_amdgcn_fmed3f(d, v1[p], v2[p]);  // new 2nd-best value
      i1[p] = c1 ? j : i1[p];
      v1[p] = fmaxf(v1[p], d);
    }
  }
#pragma unroll
  for (int mk = 1; mk <= 8; mk <<= 1)
#pragma unroll
    for (int p = 0; p < 4; ++p)
      merge2(v1[p], i1[p], v2[p], i2[p], mk);
  if (slice == 0) {
#pragma unroll
    for (int p = 0; p < 4; ++p) {
      float4 p0 = P[i1[p]];   // nearest (self)
      float4 p1 = P[i2[p]];   // 2nd nearest
      size_t row = (size_t)b * NPTS + ibase + p;
      unsigned short* xp = X + row * LDX + 512;
      float px = 0.5f * tx[p], py = 0.5f * ty[p], pz = 0.5f * tz[p];
      float vals[12] = { px, py, pz,
                         p0.x * p1.x, p0.x * p1.y, p0.x * p1.z,
                         p0.y * p1.x, p0.y * p1.y, p0.y * p1.z,
                         p0.z * p1.x, p0.z * p1.y, p0.z * p1.z };
#pragma unroll
      for (int k = 0; k < 12; ++k) xp[k] = f2bf(vals[k]);
#pragma unroll
      for (int k = 12; k < 32; ++k) xp[k] = 0;   // cols 524..543 (544+ have zero weights)
    }
  }
}

// ---------- GEMM1: H = relu(X @ W + b)   X:[M][ldx] bf16, Wt:[512][ldw] bf16 (n-major)
// BK=64: 32 MFMA per barrier pair (halves the vmcnt(0)-drain events of BK=32).
#define BM 128
#define BN 128
#define BK 64
__global__ __launch_bounds__(256) void gemm_relu_kernel(
    const unsigned short* __restrict__ Xb, const unsigned short* __restrict__ Wt,
    const float* __restrict__ bias, unsigned short* __restrict__ H,
    int K, int ldx, int ldw) {
  __shared__ unsigned short As[BM * BK];  // [chunk8][half2][row16 x k32]
  __shared__ unsigned short Bs[BN * BK];
  const int t = threadIdx.x;
  const int wave = t >> 6, lane = t & 63;
  const int m0 = blockIdx.y * BM, n0 = blockIdx.x * BN;
  const int wm = (wave >> 1) * 64, wn = (wave & 1) * 64;
  const int sr = lane >> 2;          // row within 16-row chunk
  const int sc = (lane & 3) * 8;     // k offset within 32-k half
  const int q = lane >> 4, lm = lane & 15;
  f32x4 acc[4][4] = {};
  for (int kt = 0; kt < K; kt += BK) {
#pragma unroll
    for (int r = 0; r < 2; ++r) {
      int c = r * 4 + wave;
#pragma unroll
      for (int h = 0; h < 2; ++h) {
        gload_lds16(Xb + (size_t)(m0 + c * 16 + sr) * ldx + kt + h * 32 + sc,
                    As + c * 1024 + h * 512);
        gload_lds16(Wt + (size_t)(n0 + c * 16 + sr) * ldw + kt + h * 32 + sc,
                    Bs + c * 1024 + h * 512);
      }
    }
    __syncthreads();
#pragma unroll
    for (int ks = 0; ks < 2; ++ks) {
      bf16x8 a[4], bb[4];
#pragma unroll
      for (int i = 0; i < 4; ++i)
        a[i] = *(const bf16x8*)(As + ((wm >> 4) + i) * 1024 + ks * 512 + lm * 32 + q * 8);
#pragma unroll
      for (int j = 0; j < 4; ++j)
        bb[j] = *(const bf16x8*)(Bs + ((wn >> 4) + j) * 1024 + ks * 512 + lm * 32 + q * 8);
#pragma unroll
      for (int i = 0; i < 4; ++i)
#pragma unroll
        for (int j = 0; j < 4; ++j)
          acc[i][j] = __builtin_amdgcn_mfma_f32_16x16x32_bf16(a[i], bb[j], acc[i][j], 0, 0, 0);
    }
    __syncthreads();
  }
#pragma unroll
  for (int i = 0; i < 4; ++i)
#pragma unroll
    for (int j = 0; j < 4; ++j) {
      int col = n0 + wn + j * 16 + lm;
      float bv = bias[col];
#pragma unroll
      for (int rg = 0; rg < 4; ++rg) {
        int row = m0 + wm + i * 16 + q * 4 + rg;
        float v = acc[i][j][rg] + bv;
        v = v > 0.f ? v : 0.f;
        H[(size_t)row * 512 + col] = f2bf(v);
      }
    }
}

// ---------- GEMM2: h2 = relu(H1 @ (Wr+I) + br); stage_out[row] += h2 . w2  (atomic)
__global__ __launch_bounds__(256) void gemm_res_kernel(
    const unsigned short* __restrict__ H1, const unsigned short* __restrict__ Wt,
    const float* __restrict__ br, const float* __restrict__ w2,
    float* __restrict__ so) {
  __shared__ unsigned short As[BM * BK];
  __shared__ unsigned short Bs[BN * BK];
  const int t = threadIdx.x;
  const int wave = t >> 6, lane = t & 63;
  const int m0 = blockIdx.y * BM, n0 = blockIdx.x * BN;
  const int wm = (wave >> 1) * 64, wn = (wave & 1) * 64;
  const int sr = lane >> 2, sc = (lane & 3) * 8;
  const int q = lane >> 4, lm = lane & 15;
  f32x4 acc[4][4] = {};
  for (int kt = 0; kt < 512; kt += BK) {
#pragma unroll
    for (int r = 0; r < 2; ++r) {
      int c = r * 4 + wave;
#pragma unroll
      for (int h = 0; h < 2; ++h) {
        gload_lds16(H1 + (size_t)(m0 + c * 16 + sr) * 512 + kt + h * 32 + sc,
                    As + c * 1024 + h * 512);
        gload_lds16(Wt + (size_t)(n0 + c * 16 + sr) * 512 + kt + h * 32 + sc,
                    Bs + c * 1024 + h * 512);
      }
    }
    __syncthreads();
#pragma unroll
    for (int ks = 0; ks < 2; ++ks) {
      bf16x8 a[4], bb[4];
#pragma unroll
      for (int i = 0; i < 4; ++i)
        a[i] = *(const bf16x8*)(As + ((wm >> 4) + i) * 1024 + ks * 512 + lm * 32 + q * 8);
#pragma unroll
      for (int j = 0; j < 4; ++j)
        bb[j] = *(const bf16x8*)(Bs + ((wn >> 4) + j) * 1024 + ks * 512 + lm * 32 + q * 8);
#pragma unroll
      for (int i = 0; i < 4; ++i)
#pragma unroll
        for (int j = 0; j < 4; ++j)
          acc[i][j] = __builtin_amdgcn_mfma_f32_16x16x32_bf16(a[i], bb[j], acc[i][j], 0, 0, 0);
    }
    __syncthreads();
  }
  float partial[4][4];
#pragma unroll
  for (int i = 0; i < 4; ++i)
#pragma unroll
    for (int rg = 0; rg < 4; ++rg) partial[i][rg] = 0.f;
#pragma unroll
  for (int i = 0; i < 4; ++i)
#pragma unroll
    for (int j = 0; j < 4; ++j) {
      int col = n0 + wn + j * 16 + lm;
      float bv = br[col], wv = w2[col];
#pragma unroll
      for (int rg = 0; rg < 4; ++rg) {
        float v = acc[i][j][rg] + bv;   // residual already folded into Wr+I
        v = v > 0.f ? v : 0.f;
        partial[i][rg] += v * wv;
      }
    }
#pragma unroll
  for (int i = 0; i < 4; ++i)
#pragma unroll
    for (int rg = 0; rg < 4; ++rg) {
      float s = partial[i][rg];
      s += __shfl_xor(s, 1); s += __shfl_xor(s, 2);
      s += __shfl_xor(s, 4); s += __shfl_xor(s, 8);
      if (lm == 0) atomicAdd(&so[m0 + wm + i * 16 + q * 4 + rg], s);
    }
}

// ---------- small kernels ----------
__global__ __launch_bounds__(256) void init_so_kernel(float* so, const float* b2) {
  int m = blockIdx.x * 256 + threadIdx.x;
  so[m] = b2[0];
}
__global__ __launch_bounds__(256) void update_kernel(float* std_cum, float* so,
                                                     unsigned short* X,
                                                     const float* b2_next, int first) {
  int m = blockIdx.x * 256 + threadIdx.x;
  float s = so[m];
  if (!first) s += std_cum[m];
  std_cum[m] = s;
  unsigned short* xp = X + (size_t)m * LDX + 512;
  xp[0] = f2bf(s);
#pragma unroll
  for (int k = 1; k < 12; ++k) xp[k] = 0;
  so[m] = b2_next[0];
}
__global__ __launch_bounds__(256) void finalize_kernel(float* out, const float* std_cum,
                                                       const float* so) {
  int m = blockIdx.x * 256 + threadIdx.x;
  out[m] = std_cum[m] + so[m];
}

extern "C" void kernel_launch(void* const* d_in, const int* in_sizes, int n_in,
                              void* d_out, int out_size, void* d_ws, size_t ws_size,
                              hipStream_t stream) {
  const int B = 8, N = NPTS, M = B * N;
  const float* latent = (const float*)d_in[0];
  const float* rp = (const float*)d_in[1];
  const float* w1[3] = {(const float*)d_in[2], (const float*)d_in[8], (const float*)d_in[14]};
  const float* b1[3] = {(const float*)d_in[3], (const float*)d_in[9], (const float*)d_in[15]};
  const float* wr[3] = {(const float*)d_in[4], (const float*)d_in[10], (const float*)d_in[16]};
  const float* br[3] = {(const float*)d_in[5], (const float*)d_in[11], (const float*)d_in[17]};
  const float* w2[3] = {(const float*)d_in[6], (const float*)d_in[12], (const float*)d_in[18]};
  const float* b2[3] = {(const float*)d_in[7], (const float*)d_in[13], (const float*)d_in[19]};

  char* ws = (char*)d_ws;
  auto carve = [&](size_t bytes) {
    char* p = ws;
    ws += (bytes + 255) & ~(size_t)255;
    return p;
  };
  unsigned short* X  = (unsigned short*)carve((size_t)M * LDX * 2);
  unsigned short* H1 = (unsigned short*)carve((size_t)M * 512 * 2);
  unsigned short* W1t[3], *Wrt[3];
  for (int s = 0; s < 3; ++s) W1t[s] = (unsigned short*)carve((size_t)512 * LDX * 2);
  for (int s = 0; s < 3; ++s) Wrt[s] = (unsigned short*)carve((size_t)512 * 512 * 2);
  float* std_cum = (float*)carve((size_t)M * 4);
  float* so      = (float*)carve((size_t)M * 4);

  // all 6 weights -> bf16 transposed [n][k] in one launch (Wr gets +I fold)
  convw6_kernel<<<dim3(LDX / 32, 16, 6), 256, 0, stream>>>(
      w1[0], w1[1], w1[2], wr[0], wr[1], wr[2],
      W1t[0], W1t[1], W1t[2], Wrt[0], Wrt[1], Wrt[2]);
  conv_latent_kernel<<<(M * 128) / 256, 256, 0, stream>>>(latent, X);
  knn_kernel<<<dim3(N / 128, B), 512, 0, stream>>>(rp, X);
  init_so_kernel<<<M / 256, 256, 0, stream>>>(so, b2[0]);

  for (int s = 0; s < 3; ++s) {
    gemm_relu_kernel<<<dim3(4, M / BM), 256, 0, stream>>>(X, W1t[s], b1[s], H1, LDX, LDX, LDX);
    gemm_res_kernel<<<dim3(4, M / BM), 256, 0, stream>>>(H1, Wrt[s], br[s], w2[s], so);
    if (s < 2)
      update_kernel<<<M / 256, 256, 0, stream>>>(std_cum, so, X, b2[s + 1], s == 0 ? 1 : 0);
  }
  finalize_kernel<<<M / 256, 256, 0, stream>>>((float*)d_out, std_cum, so);
}